// Round 9
// baseline (5442.106 us; speedup 1.0000x reference)
//
#include <hip/hip_runtime.h>
#include <math.h>

static constexpr int V  = 1024;
static constexpr int NH = 256;
static constexpr int B  = 128;
static constexpr int T  = 512;
static constexpr size_t BV  = (size_t)B * V;
static constexpr size_t YSZ = (size_t)T * B * V;   // 67,108,864

typedef _Float16 h8 __attribute__((ext_vector_type(8)));
typedef float f32x4 __attribute__((ext_vector_type(4)));
typedef unsigned u32;

#define MFMA16(a, b, c) __builtin_amdgcn_mfma_f32_16x16x32_f16((a), (b), (c), 0, 0, 0)
#define ALOADU(p)  __hip_atomic_load((const u32*)(p),  __ATOMIC_RELAXED, __HIP_MEMORY_SCOPE_AGENT)
#define ASTOREU(p, v) __hip_atomic_store((u32*)(p), (v), __ATOMIC_RELAXED, __HIP_MEMORY_SCOPE_AGENT)

__device__ __forceinline__ float fast_sigmoid(float x) {
    float a = fminf(-1.442695041f * x, 126.0f);
    return __builtin_amdgcn_rcpf(1.0f + __builtin_amdgcn_exp2f(a));
}

// pack f32 h -> (lo16<<16)|hi16 split-f16 (lo pre-scaled 2048)
__device__ __forceinline__ u32 packh(float h) {
    _Float16 hi = (_Float16)h;
    _Float16 lo = (_Float16)((h - (float)hi) * 2048.0f);
    unsigned short a = __builtin_bit_cast(unsigned short, hi);
    unsigned short b = __builtin_bit_cast(unsigned short, lo);
    return ((u32)b << 16) | a;
}

// Swizzled LDS address: row-major f16 plane, rowStride bytes/row,
// 16B-chunk XOR swizzle to spread banks (both write & read use this).
__device__ __forceinline__ void* lswz(char* base, int row, int k, int rowStride) {
    return base + row * rowStride + ((k * 2) ^ ((row & 7) << 4));
}

__device__ __forceinline__ float sel4(f32x4 p, int i) {
    float r = p[0];
    r = (i == 1) ? p[1] : r;
    r = (i == 2) ? p[2] : r;
    r = (i == 3) ? p[3] : r;
    return r;
}
__device__ __forceinline__ float pick4(float a0, float a1, float a2, float a3, int i) {
    float r = a0;
    r = (i == 1) ? a1 : r;
    r = (i == 2) ? a2 : r;
    r = (i == 3) ? a3 : r;
    return r;
}

// ---------------------------------------------------------------------------
// ws layout (bytes):
// 0        pk2  half[2][64][16][64][8]   2,097,152
// 2097152  pk1  half[2][64][ 8][64][8]   1,048,576
// 3145728  pkY  half[2][64][ 8][64][8]   1,048,576
// 4194304  bp2  f32[1024]
// 4198400  bp1  f32[1024]
// 4202496  pkH1 u32[32768]   (packed H1in)
// 4333568  pkH2 u32[32768]
// 4464640  flag1 u32[512*512]  (t, mp*64+np*8+wq)
// 5513216  flag2 u32[512*512]
// ---------------------------------------------------------------------------

__global__ __launch_bounds__(256) void k_prep(
    const float* __restrict__ W1f, const float* __restrict__ W1i,
    const float* __restrict__ W1o, const float* __restrict__ W1c,
    const float* __restrict__ W2f, const float* __restrict__ W2i,
    const float* __restrict__ W2o, const float* __restrict__ W2c,
    const float* __restrict__ Wout,
    const float* __restrict__ b1f, const float* __restrict__ b1i,
    const float* __restrict__ b1o, const float* __restrict__ b1c,
    const float* __restrict__ b2f, const float* __restrict__ b2i,
    const float* __restrict__ b2o, const float* __restrict__ b2c,
    _Float16* __restrict__ pk2, _Float16* __restrict__ pk1,
    _Float16* __restrict__ pkY, float* __restrict__ bp2, float* __restrict__ bp1)
{
    int idx = blockIdx.x * 256 + threadIdx.x;
    if (idx < 2097152) {
        int KB, e, rowoff = 0;
        bool vocabN = false;
        _Float16* dst;
        if (idx < 1048576)      { e = idx;            KB = 16; dst = pk2; }
        else if (idx < 1572864) { e = idx - 1048576;  KB = 8;  dst = pk1; rowoff = V; }
        else                    { e = idx - 1572864;  KB = 8;  dst = pkY; vocabN = true; }
        int S = 64 * KB * 512;
        int split = e / S, r = e % S;
        int grp = r / (KB * 512);
        int r2  = r % (KB * 512);
        int kb = r2 >> 9, lane = (r2 >> 3) & 63, i = r2 & 7;
        int n = grp * 16 + (lane & 15);
        int k = kb * 32 + (lane >> 4) * 8 + i;
        float val;
        if (vocabN) {
            val = Wout[(size_t)k * 1024 + n];
        } else {
            int j = n >> 2, g = n & 3;
            const float* W = (KB == 16)
                ? (g == 0 ? W2f : g == 1 ? W2i : g == 2 ? W2o : W2c)
                : (g == 0 ? W1f : g == 1 ? W1i : g == 2 ? W1o : W1c);
            val = W[(size_t)(rowoff + k) * NH + j];
        }
        _Float16 hi = (_Float16)val;
        dst[e] = split ? (_Float16)((val - (float)hi) * 2048.0f) : hi;
    } else {
        int bi = idx - 2097152;
        if (bi < 1024) {
            int j = bi >> 2, g = bi & 3;
            bp2[bi] = (g == 0 ? b2f : g == 1 ? b2i : g == 2 ? b2o : b2c)[j];
        } else if (bi < 2048) {
            int b2_ = bi - 1024;
            int j = b2_ >> 2, g = b2_ & 3;
            bp1[b2_] = (g == 0 ? b1f : g == 1 ? b1i : g == 2 ? b1o : b1c)[j];
        }
    }
}

__global__ __launch_bounds__(256) void k_pack(
    const float* __restrict__ H1in, const float* __restrict__ H2in,
    u32* __restrict__ pkH1, u32* __restrict__ pkH2)
{
    int i = blockIdx.x * 256 + threadIdx.x;   // 65536
    if (i < 32768) pkH1[i] = packh(H1in[i]);
    else           pkH2[i - 32768] = packh(H2in[i - 32768]);
}

__global__ __launch_bounds__(256) void k_zero(u32* __restrict__ f) {
    f[blockIdx.x * 256 + threadIdx.x] = 0;    // 524288 = both flag arrays
}

// ---------------------------------------------------------------------------
// Merged kernel: blocks 0..127 = persistent recurrence (64 cell2 + 64 cell1),
// blocks 128..639 = output GEMM (one t each), gated on flags.
// ---------------------------------------------------------------------------
__global__ __launch_bounds__(512, 1) void k_main(
    const int* __restrict__ X,
    const float* __restrict__ C1in, const float* __restrict__ C2in,
    float* __restrict__ y,
    float* __restrict__ H1t, float* __restrict__ C1t,
    float* __restrict__ H2t, float* __restrict__ C2t,
    const _Float16* __restrict__ pk2, const _Float16* __restrict__ pk1,
    const _Float16* __restrict__ pkY,
    const float* __restrict__ bp2, const float* __restrict__ bp1,
    const u32* __restrict__ pkH1, const u32* __restrict__ pkH2,
    u32* __restrict__ flag1, u32* __restrict__ flag2,
    const float* __restrict__ W1f, const float* __restrict__ W1i,
    const float* __restrict__ W1o, const float* __restrict__ W1c,
    const float* __restrict__ bout)
{
    __shared__ __align__(16) char smem[131072];
    const int bid = blockIdx.x, tid = threadIdx.x;
    const int lane = tid & 63, wv = tid >> 6;
    const int col = lane & 15, kg = lane >> 4;
    u32* yu = (u32*)y;

    if (bid < 128) {
        // ================= persistent recurrence =================
        const bool isC2 = bid < 64;
        const int mp = (bid & 63) >> 3, np = bid & 7, r0 = mp * 16;
        const int wq = wv;
        const int orow = ((lane >> 4) << 2) | (lane & 3);   // 0..15
        const int jq = (lane >> 2) & 3;
        const int jloc = wq * 4 + jq;                        // 0..31
        const int jglob = np * 32 + jloc;
        const int brow = r0 + orow;
        const int c3 = lane & 3;
        const int srow = tid >> 5;                           // 0..15

        if (isC2) {
            h8 wh[16], wl[16];
            {
                const _Float16* pB = pk2 + ((size_t)(np * 8 + wq) * 16 * 64 + lane) * 8;
                #pragma unroll
                for (int kb = 0; kb < 16; ++kb) {
                    wh[kb] = *(const h8*)(pB + (size_t)kb * 512);
                    wl[kb] = *(const h8*)(pB + 524288 + (size_t)kb * 512);
                }
                #pragma unroll
                for (int kb = 0; kb < 16; ++kb)
                    asm volatile("" : "+v"(wh[kb]), "+v"(wl[kb]));
            }
            float creg = C2in[brow * NH + jglob];
            const f32x4 bb = *(const f32x4*)&bp2[np * 128 + jloc * 4];
            const int sc0 = (tid & 31) * 16;     // 0..496
            const bool sH1 = sc0 < 256;

            for (int t = 0; t < T; ++t) {
                char* AHb = smem + (t & 1) * 16384;
                char* ALb = smem + 32768 + (t & 1) * 16384;
                u32 uu[16];
                // --- wait h2(t-1) flags, load h2 half ---
                if (t) {
                    const u32* f = &flag2[(size_t)(t - 1) * 512 + mp * 64 + lane];
                    while (ALOADU(f) == 0) __builtin_amdgcn_s_sleep(2);
                }
                if (!sH1) {
                    const u32* sb = t ? (yu + (size_t)(t - 1) * BV + (size_t)(r0 + srow) * V + (sc0 - 256))
                                      : (pkH2 + (r0 + srow) * NH + (sc0 - 256));
                    #pragma unroll
                    for (int i = 0; i < 16; ++i) uu[i] = ALOADU(sb + i);
                }
                // --- wait h1(t) flags, load h1 half ---
                {
                    const u32* f = &flag1[(size_t)t * 512 + mp * 64 + lane];
                    while (ALOADU(f) == 0) __builtin_amdgcn_s_sleep(2);
                }
                if (sH1) {
                    const u32* sb = yu + (size_t)t * BV + (size_t)(r0 + srow) * V + 256 + sc0;
                    #pragma unroll
                    for (int i = 0; i < 16; ++i) uu[i] = ALOADU(sb + i);
                }
                // unpack -> LDS
                u32 hw[8], lw[8];
                #pragma unroll
                for (int i = 0; i < 8; ++i) {
                    u32 a = uu[2 * i], b = uu[2 * i + 1];
                    hw[i] = (a & 0xFFFFu) | (b << 16);
                    lw[i] = (a >> 16) | (b & 0xFFFF0000u);
                }
                *(uint4*)lswz(AHb, srow, sc0,     1024) = *(uint4*)&hw[0];
                *(uint4*)lswz(AHb, srow, sc0 + 8, 1024) = *(uint4*)&hw[4];
                *(uint4*)lswz(ALb, srow, sc0,     1024) = *(uint4*)&lw[0];
                *(uint4*)lswz(ALb, srow, sc0 + 8, 1024) = *(uint4*)&lw[4];
                __syncthreads();

                f32x4 a0 = {0.f, 0.f, 0.f, 0.f}, a1 = a0, a2 = a0;
                #pragma unroll
                for (int kb = 0; kb < 16; ++kb) {
                    h8 ah = *(const h8*)lswz(AHb, col, kb * 32 + kg * 8, 1024);
                    h8 al = *(const h8*)lswz(ALb, col, kb * 32 + kg * 8, 1024);
                    a0 = MFMA16(ah, wh[kb], a0);
                    a1 = MFMA16(ah, wl[kb], a1);
                    a2 = MFMA16(al, wh[kb], a2);
                }
                f32x4 comb = a0 + (a1 + a2) * (1.0f / 2048.0f);
                float s0 = sel4(comb, c3);
                float s1 = __shfl_xor(sel4(comb, c3 ^ 1), 1);
                float s2 = __shfl_xor(sel4(comb, c3 ^ 2), 2);
                float s3 = __shfl_xor(sel4(comb, c3 ^ 3), 3);
                float pf = pick4(s0, s1, s2, s3, c3)     + bb[0];
                float pi = pick4(s0, s1, s2, s3, c3 ^ 1) + bb[1];
                float po = pick4(s0, s1, s2, s3, c3 ^ 2) + bb[2];
                float pc = pick4(s0, s1, s2, s3, c3 ^ 3) + bb[3];
                float fg = fast_sigmoid(pf), ig = fast_sigmoid(pi), og = fast_sigmoid(po);
                float ct = tanhf(pc);
                creg = fmaf(fg, creg, ig * ct);
                float h = og * tanhf(creg);
                ASTOREU(yu + (size_t)t * BV + (size_t)brow * V + jglob, packh(h));
                if (t == T - 1) { H2t[brow * NH + jglob] = h; C2t[brow * NH + jglob] = creg; }
                asm volatile("s_waitcnt vmcnt(0)" ::: "memory");
                if (lane == 0)
                    ASTOREU(&flag2[(size_t)t * 512 + mp * 64 + np * 8 + wq], 1u);
            }
        } else {
            h8 wh[8], wl[8];
            {
                const _Float16* pB = pk1 + ((size_t)(np * 8 + wq) * 8 * 64 + lane) * 8;
                #pragma unroll
                for (int kb = 0; kb < 8; ++kb) {
                    wh[kb] = *(const h8*)(pB + (size_t)kb * 512);
                    wl[kb] = *(const h8*)(pB + 262144 + (size_t)kb * 512);
                }
                #pragma unroll
                for (int kb = 0; kb < 8; ++kb)
                    asm volatile("" : "+v"(wh[kb]), "+v"(wl[kb]));
            }
            float creg = C1in[brow * NH + jglob];
            const f32x4 bb = *(const f32x4*)&bp1[np * 128 + jloc * 4];
            const int sc0 = (tid & 31) * 8;      // 0..248

            for (int t = 0; t < T; ++t) {
                char* AHb = smem + (t & 1) * 16384;
                char* ALb = smem + 32768 + (t & 1) * 16384;
                // token gathers: independent, issue early
                int tok = X[brow * T + t];
                float w1f_ = W1f[(size_t)tok * NH + jglob];
                float w1i_ = W1i[(size_t)tok * NH + jglob];
                float w1o_ = W1o[(size_t)tok * NH + jglob];
                float w1c_ = W1c[(size_t)tok * NH + jglob];

                if (t) {
                    const u32* f = &flag1[(size_t)(t - 1) * 512 + mp * 64 + lane];
                    while (ALOADU(f) == 0) __builtin_amdgcn_s_sleep(2);
                }
                const u32* sb = t ? (yu + (size_t)(t - 1) * BV + (size_t)(r0 + srow) * V + 256 + sc0)
                                  : (pkH1 + (r0 + srow) * NH + sc0);
                u32 uu[8];
                #pragma unroll
                for (int i = 0; i < 8; ++i) uu[i] = ALOADU(sb + i);
                u32 hw[4], lw[4];
                #pragma unroll
                for (int i = 0; i < 4; ++i) {
                    u32 a = uu[2 * i], b = uu[2 * i + 1];
                    hw[i] = (a & 0xFFFFu) | (b << 16);
                    lw[i] = (a >> 16) | (b & 0xFFFF0000u);
                }
                *(uint4*)lswz(AHb, srow, sc0, 1024) = *(uint4*)&hw[0];
                *(uint4*)lswz(ALb, srow, sc0, 1024) = *(uint4*)&lw[0];
                __syncthreads();

                f32x4 a0 = {0.f, 0.f, 0.f, 0.f}, a1 = a0, a2 = a0;
                #pragma unroll
                for (int kb = 0; kb < 8; ++kb) {
                    h8 ah = *(const h8*)lswz(AHb, col, kb * 32 + kg * 8, 1024);
                    h8 al = *(const h8*)lswz(ALb, col, kb * 32 + kg * 8, 1024);
                    a0 = MFMA16(ah, wh[kb], a0);
                    a1 = MFMA16(ah, wl[kb], a1);
                    a2 = MFMA16(al, wh[kb], a2);
                }
                f32x4 comb = a0 + (a1 + a2) * (1.0f / 2048.0f);
                float s0 = sel4(comb, c3);
                float s1 = __shfl_xor(sel4(comb, c3 ^ 1), 1);
                float s2 = __shfl_xor(sel4(comb, c3 ^ 2), 2);
                float s3 = __shfl_xor(sel4(comb, c3 ^ 3), 3);
                float pf = pick4(s0, s1, s2, s3, c3)     + bb[0] + w1f_;
                float pi = pick4(s0, s1, s2, s3, c3 ^ 1) + bb[1] + w1i_;
                float po = pick4(s0, s1, s2, s3, c3 ^ 2) + bb[2] + w1o_;
                float pc = pick4(s0, s1, s2, s3, c3 ^ 3) + bb[3] + w1c_;
                float fg = fast_sigmoid(pf), ig = fast_sigmoid(pi), og = fast_sigmoid(po);
                float ct = tanhf(pc);
                creg = fmaf(fg, creg, ig * ct);
                float h = og * tanhf(creg);
                ASTOREU(yu + (size_t)t * BV + (size_t)brow * V + 256 + jglob, packh(h));
                if (t == T - 1) { H1t[brow * NH + jglob] = h; C1t[brow * NH + jglob] = creg; }
                asm volatile("s_waitcnt vmcnt(0)" ::: "memory");
                if (lane == 0)
                    ASTOREU(&flag1[(size_t)t * 512 + mp * 64 + np * 8 + wq], 1u);
            }
        }
    } else {
        // ================= output GEMM, one timestep per block =================
        const int t = bid - 128;                 // 0..511
        const int rt2 = wv & 3, nph = wv >> 2;
        // gate: all flags of t+1 (both tiers) + flag2[t]. wave0 polls, others wait.
        if (wv == 0) {
            for (int i = 0; i < 8; ++i) {
                if (t < 511) {
                    const u32* f1 = &flag1[(size_t)(t + 1) * 512 + lane * 8 + i];
                    while (ALOADU(f1) == 0) __builtin_amdgcn_s_sleep(64);
                    const u32* f2 = &flag2[(size_t)(t + 1) * 512 + lane * 8 + i];
                    while (ALOADU(f2) == 0) __builtin_amdgcn_s_sleep(64);
                }
                const u32* f0 = &flag2[(size_t)t * 512 + lane * 8 + i];
                while (ALOADU(f0) == 0) __builtin_amdgcn_s_sleep(64);
            }
        }
        __syncthreads();
        // stage h2(t): 128 rows x 256 packed u32 -> swizzled LDS planes
        {
            const int row = tid >> 2, c0 = (tid & 3) * 64;
            const u32* sb = yu + (size_t)(t * B + row) * V + c0;
            #pragma unroll
            for (int ch = 0; ch < 8; ++ch) {
                u32 uu[8];
                #pragma unroll
                for (int i = 0; i < 8; ++i) uu[i] = ALOADU(sb + ch * 8 + i);
                u32 hw[4], lw[4];
                #pragma unroll
                for (int i = 0; i < 4; ++i) {
                    u32 a = uu[2 * i], b = uu[2 * i + 1];
                    hw[i] = (a & 0xFFFFu) | (b << 16);
                    lw[i] = (a >> 16) | (b & 0xFFFF0000u);
                }
                *(uint4*)lswz(smem,         row, c0 + ch * 8, 512) = *(uint4*)&hw[0];
                *(uint4*)lswz(smem + 65536, row, c0 + ch * 8, 512) = *(uint4*)&lw[0];
            }
        }
        __syncthreads();
        for (int npi = 0; npi < 4; ++npi) {
            const int npass = nph * 4 + npi;
            f32x4 aA[2][8], aB[2][8];
            #pragma unroll
            for (int nt = 0; nt < 8; ++nt) {
                aA[0][nt] = (f32x4){0.f,0.f,0.f,0.f}; aA[1][nt] = aA[0][nt];
                aB[0][nt] = aA[0][nt]; aB[1][nt] = aA[0][nt];
            }
            for (int kb = 0; kb < 8; ++kb) {
                h8 ah0 = *(const h8*)lswz(smem,         rt2 * 32 + col,      kb * 32 + kg * 8, 512);
                h8 al0 = *(const h8*)lswz(smem + 65536, rt2 * 32 + col,      kb * 32 + kg * 8, 512);
                h8 ah1 = *(const h8*)lswz(smem,         rt2 * 32 + 16 + col, kb * 32 + kg * 8, 512);
                h8 al1 = *(const h8*)lswz(smem + 65536, rt2 * 32 + 16 + col, kb * 32 + kg * 8, 512);
                #pragma unroll
                for (int nt = 0; nt < 8; ++nt) {
                    const _Float16* pb = pkY + ((size_t)((npass * 8 + nt) * 8 + kb) * 64 + lane) * 8;
                    h8 bh = *(const h8*)pb;
                    h8 bl = *(const h8*)(pb + 262144);
                    aA[0][nt] = MFMA16(ah0, bh, aA[0][nt]);
                    aB[0][nt] = MFMA16(ah0, bl, aB[0][nt]);
                    aB[0][nt] = MFMA16(al0, bh, aB[0][nt]);
                    aA[1][nt] = MFMA16(ah1, bh, aA[1][nt]);
                    aB[1][nt] = MFMA16(ah1, bl, aB[1][nt]);
                    aB[1][nt] = MFMA16(al1, bh, aB[1][nt]);
                }
            }
            #pragma unroll
            for (int mh = 0; mh < 2; ++mh)
            #pragma unroll
            for (int nt = 0; nt < 8; ++nt) {
                int n = npass * 128 + nt * 16 + col;
                float bbo = bout[n];
                #pragma unroll
                for (int q = 0; q < 4; ++q)
                    y[(size_t)(t * B + rt2 * 32 + mh * 16 + kg * 4 + q) * V + n] =
                        aA[mh][nt][q] + aB[mh][nt][q] * (1.0f / 2048.0f) + bbo;
            }
        }
    }
}

// ---------------- launch ----------------
extern "C" void kernel_launch(void* const* d_in, const int* in_sizes, int n_in,
                              void* d_out, int out_size, void* d_ws, size_t ws_size,
                              hipStream_t stream) {
    const int*   X    = (const int*)  d_in[0];
    const float* H1in = (const float*)d_in[1];
    const float* C1in = (const float*)d_in[2];
    const float* H2in = (const float*)d_in[3];
    const float* C2in = (const float*)d_in[4];
    const float* W1f = (const float*)d_in[5];  const float* b1f = (const float*)d_in[6];
    const float* W1i = (const float*)d_in[7];  const float* b1i = (const float*)d_in[8];
    const float* W1o = (const float*)d_in[9];  const float* b1o = (const float*)d_in[10];
    const float* W1c = (const float*)d_in[11]; const float* b1c = (const float*)d_in[12];
    const float* W2f = (const float*)d_in[13]; const float* b2f = (const float*)d_in[14];
    const float* W2i = (const float*)d_in[15]; const float* b2i = (const float*)d_in[16];
    const float* W2o = (const float*)d_in[17]; const float* b2o = (const float*)d_in[18];
    const float* W2c = (const float*)d_in[19]; const float* b2c = (const float*)d_in[20];
    const float* Wout = (const float*)d_in[21]; const float* bout = (const float*)d_in[22];

    float* y   = (float*)d_out;
    float* H1t = y + YSZ;
    float* C1t = y + YSZ + 1 * 32768;
    float* H2t = y + YSZ + 2 * 32768;
    float* C2t = y + YSZ + 3 * 32768;

    char* ws = (char*)d_ws;
    _Float16* pk2 = (_Float16*)ws;
    _Float16* pk1 = pk2 + 1048576;
    _Float16* pkY = pk1 + 524288;
    float* bp2 = (float*)(ws + 4194304);
    float* bp1 = bp2 + 1024;
    u32* pkH1  = (u32*)(ws + 4202496);
    u32* pkH2  = (u32*)(ws + 4333568);
    u32* flag1 = (u32*)(ws + 4464640);
    u32* flag2 = (u32*)(ws + 5513216);

    k_prep<<<8200, 256, 0, stream>>>(W1f, W1i, W1o, W1c, W2f, W2i, W2o, W2c, Wout,
                                     b1f, b1i, b1o, b1c, b2f, b2i, b2o, b2c,
                                     pk2, pk1, pkY, bp2, bp1);
    k_pack<<<256, 256, 0, stream>>>(H1in, H2in, pkH1, pkH2);
    k_zero<<<2048, 256, 0, stream>>>(flag1);

    k_main<<<640, 512, 0, stream>>>(X, C1in, C2in, y,
                                    H1t, C1t, H2t, C2t,
                                    pk2, pk1, pkY, bp2, bp1,
                                    pkH1, pkH2, flag1, flag2,
                                    W1f, W1i, W1o, W1c, bout);
}

// Round 10
// 2222.142 us; speedup vs baseline: 2.4490x; 2.4490x over previous
//
#include <hip/hip_runtime.h>
#include <math.h>

static constexpr int V  = 1024;
static constexpr int NH = 256;
static constexpr int B  = 128;
static constexpr int T  = 512;
static constexpr size_t BV  = (size_t)B * V;
static constexpr size_t YSZ = (size_t)T * B * V;   // 67,108,864
static constexpr unsigned SENT = 0xFFC0DEADu;      // NaN payload; h in (-1,1) never equals it

typedef _Float16 h8 __attribute__((ext_vector_type(8)));
typedef _Float16 h4 __attribute__((ext_vector_type(4)));
typedef float f32x4 __attribute__((ext_vector_type(4)));

#define MFMA16(a, b, c) __builtin_amdgcn_mfma_f32_16x16x32_f16((a), (b), (c), 0, 0, 0)
#define ALOAD(p)  __hip_atomic_load((p),  __ATOMIC_RELAXED, __HIP_MEMORY_SCOPE_AGENT)
#define ASTORE(p, v) __hip_atomic_store((p), (v), __ATOMIC_RELAXED, __HIP_MEMORY_SCOPE_AGENT)

__device__ __forceinline__ float fast_sigmoid(float x) {
    float a = fminf(-1.442695041f * x, 126.0f);
    return __builtin_amdgcn_rcpf(1.0f + __builtin_amdgcn_exp2f(a));
}

// Split-f16: x = hi + lo*2^-11, lo pre-scaled by 2048. Dot = hi*hi + (hi*lo + lo*hi)*2^-11.
// d_out layout (f32): y[T*B][V], tails: H1, C1, H2, C2 (each B*NH).
// Stash: h2(t)->y[t][0:256], h1(t)->y[t][256:512]; sync = data-as-flag (SENT),
// relaxed agent atomics both sides (LLC is the sync point). 256 blocks x 512 thr.
// WEIGHTS: loaded via inline-asm global_load_dwordx4 -> the compiler cannot
// rematerialize them into the t-loop (the R5-R8 FETCH~1GB failure mode); one
// s_waitcnt vmcnt(0) asm with "+v" ties consumes before first MFMA use.

__global__ __launch_bounds__(256) void k_prep(
    const float* __restrict__ W1f, const float* __restrict__ W1i,
    const float* __restrict__ W1o, const float* __restrict__ W1c,
    const float* __restrict__ W2f, const float* __restrict__ W2i,
    const float* __restrict__ W2o, const float* __restrict__ W2c,
    const float* __restrict__ Wout,
    const float* __restrict__ b1f, const float* __restrict__ b1i,
    const float* __restrict__ b1o, const float* __restrict__ b1c,
    const float* __restrict__ b2f, const float* __restrict__ b2i,
    const float* __restrict__ b2o, const float* __restrict__ b2c,
    _Float16* __restrict__ pk2, _Float16* __restrict__ pk1,
    _Float16* __restrict__ pkY, float* __restrict__ bp2, float* __restrict__ bp1)
{
    int idx = blockIdx.x * 256 + threadIdx.x;
    if (idx < 2097152) {
        int KB, e, rowoff = 0;
        bool vocabN = false;
        _Float16* dst;
        if (idx < 1048576)      { e = idx;            KB = 16; dst = pk2; }
        else if (idx < 1572864) { e = idx - 1048576;  KB = 8;  dst = pk1; rowoff = V; }
        else                    { e = idx - 1572864;  KB = 8;  dst = pkY; vocabN = true; }
        int S = 64 * KB * 512;
        int split = e / S, r = e % S;
        int grp = r / (KB * 512);
        int r2  = r % (KB * 512);
        int kb = r2 >> 9, lane = (r2 >> 3) & 63, i = r2 & 7;
        int n = grp * 16 + (lane & 15);
        int k = kb * 32 + (lane >> 4) * 8 + i;
        float val;
        if (vocabN) {
            val = Wout[(size_t)k * 1024 + n];
        } else {
            int j = n >> 2, g = n & 3;
            const float* W = (KB == 16)
                ? (g == 0 ? W2f : g == 1 ? W2i : g == 2 ? W2o : W2c)
                : (g == 0 ? W1f : g == 1 ? W1i : g == 2 ? W1o : W1c);
            val = W[(size_t)(rowoff + k) * NH + j];
        }
        _Float16 hi = (_Float16)val;
        dst[e] = split ? (_Float16)((val - (float)hi) * 2048.0f) : hi;
    } else {
        int bi = idx - 2097152;
        if (bi < 1024) {
            int j = bi >> 2, g = bi & 3;
            bp2[bi] = (g == 0 ? b2f : g == 1 ? b2i : g == 2 ? b2o : b2c)[j];
        } else if (bi < 2048) {
            int b2_ = bi - 1024;
            int j = b2_ >> 2, g = b2_ & 3;
            bp1[b2_] = (g == 0 ? b1f : g == 1 ? b1i : g == 2 ? b1o : b1c)[j];
        }
    }
}

// Fill h-stash (cols 0..511 of every y row) with sentinel.
__global__ __launch_bounds__(256) void k_sent(float* __restrict__ y) {
    const float s = __uint_as_float(SENT);
    const f32x4 sv = {s, s, s, s};
    int gid = blockIdx.x * 256 + threadIdx.x;       // 524288 threads
    for (int n = gid; n < 8388608; n += 524288) {
        int row = n >> 7, c4 = n & 127;
        *(f32x4*)&y[(size_t)row * V + c4 * 4] = sv;
    }
}

__device__ __forceinline__ void cvt4(const float* u, h4* hi4, h4* lo4) {
    h4 hi, lo;
    #pragma unroll
    for (int e = 0; e < 4; ++e) {
        _Float16 h = (_Float16)u[e];
        hi[e] = h; lo[e] = (_Float16)((u[e] - (float)h) * 2048.0f);
    }
    *hi4 = hi; *lo4 = lo;
}

// Persistent recurrence. 256 blocks x 512 thr: bid<128 -> cell2, else cell1.
// Block (mp,np): rows r0..r0+15, gate-cols np*64..+64, all t.
// Wave w: wq=w&3 (16-col group np*4+wq), kh=w>>2 (K-half).
__global__ __launch_bounds__(512, 1) void k_persist(
    const int* __restrict__ X,
    const float* __restrict__ H1in, const float* __restrict__ C1in,
    const float* __restrict__ H2in, const float* __restrict__ C2in,
    float* __restrict__ y,
    float* __restrict__ H1t, float* __restrict__ C1t,
    float* __restrict__ H2t, float* __restrict__ C2t,
    const _Float16* __restrict__ pk2, const _Float16* __restrict__ pk1,
    const float* __restrict__ bp2, const float* __restrict__ bp1,
    const float* __restrict__ W1f, const float* __restrict__ W1i,
    const float* __restrict__ W1o, const float* __restrict__ W1c)
{
    const int bid = blockIdx.x, tid = threadIdx.x;
    const bool isC2 = bid < 128;
    const int mp = (bid & 127) >> 4;    // 0..7
    const int np = bid & 15;            // 0..15
    const int r0 = mp * 16;

    __shared__ _Float16 Ah[16][520];
    __shared__ _Float16 Al[16][520];
    __shared__ float    preA[16][64];
    __shared__ float    preB[16][64];

    const int wave = tid >> 6, lane = tid & 63;
    const int wq = wave & 3, kh = wave >> 2;
    const int col = lane & 15, kg = lane >> 4;
    const _Float16* arow_h = &Ah[col][kg * 8];
    const _Float16* arow_l = &Al[col][kg * 8];
    const int n_local = wq * 16 + col;

    // combine ownership (threads 0..255 only)
    const int cr = tid >> 4, cjl = tid & 15;
    const int cb = r0 + (cr & 15), cjg = np * 16 + cjl;

    if (isC2) {
        // ---- per-wave weights via remat-proof asm loads: 16 h8 = 64 VGPR ----
        h8 wh[8], wl[8];
        {
            const _Float16* pB = pk2 + ((size_t)((np * 4 + wq) * 16 + kh * 8) * 64 + lane) * 8;
            #pragma unroll
            for (int kb8 = 0; kb8 < 8; ++kb8) {
                asm volatile("global_load_dwordx4 %0, %1, off"
                             : "=v"(wh[kb8]) : "v"(pB + (size_t)kb8 * 512));
                asm volatile("global_load_dwordx4 %0, %1, off"
                             : "=v"(wl[kb8]) : "v"(pB + 524288 + (size_t)kb8 * 512));
            }
            asm volatile("s_waitcnt vmcnt(0)"
                : "+v"(wh[0]), "+v"(wh[1]), "+v"(wh[2]), "+v"(wh[3]),
                  "+v"(wh[4]), "+v"(wh[5]), "+v"(wh[6]), "+v"(wh[7]),
                  "+v"(wl[0]), "+v"(wl[1]), "+v"(wl[2]), "+v"(wl[3]),
                  "+v"(wl[4]), "+v"(wl[5]), "+v"(wl[6]), "+v"(wl[7]));
        }
        float creg = (tid < 256) ? C2in[cb * NH + cjg] : 0.f;
        const f32x4 bb = *(const f32x4*)&bp2[np * 64 + cjl * 4];

        // staging: sk4 = tid&127 (cols: <64 -> h1(t), >=64 -> h2(t-1)); rows g*4+srb
        const int sk4 = tid & 127;
        const int srb = tid >> 7;   // 0..3
        const bool isH1 = sk4 < 64;

        for (int t = 0; t < T; ++t) {
            // ---- batched poll+stage ----
            const float* sp[4];
            float u[4][4];
            const bool pollable = isH1 || (t > 0);
            #pragma unroll
            for (int g = 0; g < 4; ++g) {
                const int r = g * 4 + srb;
                sp[g] = isH1 ? (y + (size_t)t * BV + (size_t)(r0 + r) * V + 256 + sk4 * 4)
                       : (t ? (y + (size_t)(t - 1) * BV + (size_t)(r0 + r) * V + (sk4 - 64) * 4)
                            : (H2in + (size_t)(r0 + r) * NH + (sk4 - 64) * 4));
            }
            #pragma unroll
            for (int g = 0; g < 4; ++g)
                #pragma unroll
                for (int e = 0; e < 4; ++e) u[g][e] = ALOAD(sp[g] + e);
            if (pollable) {
                for (;;) {
                    bool any = false;
                    #pragma unroll
                    for (int g = 0; g < 4; ++g)
                        #pragma unroll
                        for (int e = 0; e < 4; ++e)
                            any = any || (__float_as_uint(u[g][e]) == SENT);
                    if (!any) break;
                    __builtin_amdgcn_s_sleep(1);
                    #pragma unroll
                    for (int g = 0; g < 4; ++g)
                        #pragma unroll
                        for (int e = 0; e < 4; ++e)
                            if (__float_as_uint(u[g][e]) == SENT) u[g][e] = ALOAD(sp[g] + e);
                }
            }
            #pragma unroll
            for (int g = 0; g < 4; ++g) {
                const int r = g * 4 + srb;
                cvt4(u[g], (h4*)&Ah[r][sk4 * 4], (h4*)&Al[r][sk4 * 4]);
            }
            __syncthreads();

            f32x4 a0 = {0.f, 0.f, 0.f, 0.f}, a1 = a0, a2 = a0;
            #pragma unroll
            for (int kb8 = 0; kb8 < 8; ++kb8) {
                const int kbg = kh * 8 + kb8;
                h8 ah = *(const h8*)(arow_h + kbg * 32);
                h8 al = *(const h8*)(arow_l + kbg * 32);
                a0 = MFMA16(ah, wh[kb8], a0);
                a1 = MFMA16(ah, wl[kb8], a1);
                a2 = MFMA16(al, wh[kb8], a2);
            }
            float* pre = kh ? &preB[0][0] : &preA[0][0];
            #pragma unroll
            for (int q = 0; q < 4; ++q)
                pre[(kg * 4 + q) * 64 + n_local] = a0[q] + (a1[q] + a2[q]) * (1.0f / 2048.0f);
            __syncthreads();

            if (tid < 256) {
                f32x4 gA = *(const f32x4*)&preA[cr][cjl * 4];
                f32x4 gB = *(const f32x4*)&preB[cr][cjl * 4];
                float pf = gA[0] + gB[0] + bb[0], pi = gA[1] + gB[1] + bb[1];
                float po = gA[2] + gB[2] + bb[2], pc = gA[3] + gB[3] + bb[3];
                float fg = fast_sigmoid(pf);
                float ig = fast_sigmoid(pi);
                float og = fast_sigmoid(po);
                float ct = tanhf(pc);
                creg = fmaf(fg, creg, ig * ct);
                float h = og * tanhf(creg);
                ASTORE(&y[(size_t)t * BV + (size_t)cb * V + cjg], h);
                if (t == T - 1) { H2t[cb * NH + cjg] = h; C2t[cb * NH + cjg] = creg; }
            }
        }
    } else {
        // ---- per-wave weights via remat-proof asm loads: 8 h8 = 32 VGPR ----
        h8 wh[4], wl[4];
        {
            const _Float16* pB = pk1 + ((size_t)((np * 4 + wq) * 8 + kh * 4) * 64 + lane) * 8;
            #pragma unroll
            for (int kb4 = 0; kb4 < 4; ++kb4) {
                asm volatile("global_load_dwordx4 %0, %1, off"
                             : "=v"(wh[kb4]) : "v"(pB + (size_t)kb4 * 512));
                asm volatile("global_load_dwordx4 %0, %1, off"
                             : "=v"(wl[kb4]) : "v"(pB + 262144 + (size_t)kb4 * 512));
            }
            asm volatile("s_waitcnt vmcnt(0)"
                : "+v"(wh[0]), "+v"(wh[1]), "+v"(wh[2]), "+v"(wh[3]),
                  "+v"(wl[0]), "+v"(wl[1]), "+v"(wl[2]), "+v"(wl[3]));
        }
        float creg = (tid < 256) ? C1in[cb * NH + cjg] : 0.f;
        const f32x4 bb = *(const f32x4*)&bp1[np * 64 + cjl * 4];

        // staging: sk4 = tid&63, rows srb + g*8
        const int sk4 = tid & 63;
        const int srb = tid >> 6;   // 0..7

        for (int t = 0; t < T; ++t) {
            // early-issue token-row gathers (consumed in combine)
            float w1f_ = 0.f, w1i_ = 0.f, w1o_ = 0.f, w1c_ = 0.f;
            if (tid < 256) {
                int tok = X[cb * T + t];
                w1f_ = W1f[(size_t)tok * NH + cjg];
                w1i_ = W1i[(size_t)tok * NH + cjg];
                w1o_ = W1o[(size_t)tok * NH + cjg];
                w1c_ = W1c[(size_t)tok * NH + cjg];
            }
            // ---- batched poll+stage h1(t-1) ----
            const float* sp[2];
            float u[2][4];
            #pragma unroll
            for (int g = 0; g < 2; ++g) {
                const int r = g * 8 + srb;
                sp[g] = t ? (y + (size_t)(t - 1) * BV + (size_t)(r0 + r) * V + 256 + sk4 * 4)
                          : (H1in + (size_t)(r0 + r) * NH + sk4 * 4);
            }
            #pragma unroll
            for (int g = 0; g < 2; ++g)
                #pragma unroll
                for (int e = 0; e < 4; ++e) u[g][e] = ALOAD(sp[g] + e);
            if (t) {
                for (;;) {
                    bool any = false;
                    #pragma unroll
                    for (int g = 0; g < 2; ++g)
                        #pragma unroll
                        for (int e = 0; e < 4; ++e)
                            any = any || (__float_as_uint(u[g][e]) == SENT);
                    if (!any) break;
                    __builtin_amdgcn_s_sleep(1);
                    #pragma unroll
                    for (int g = 0; g < 2; ++g)
                        #pragma unroll
                        for (int e = 0; e < 4; ++e)
                            if (__float_as_uint(u[g][e]) == SENT) u[g][e] = ALOAD(sp[g] + e);
                }
            }
            #pragma unroll
            for (int g = 0; g < 2; ++g) {
                const int r = g * 8 + srb;
                cvt4(u[g], (h4*)&Ah[r][sk4 * 4], (h4*)&Al[r][sk4 * 4]);
            }
            __syncthreads();

            f32x4 a0 = {0.f, 0.f, 0.f, 0.f}, a1 = a0, a2 = a0;
            #pragma unroll
            for (int kb4 = 0; kb4 < 4; ++kb4) {
                const int kbg = kh * 4 + kb4;
                h8 ah = *(const h8*)(arow_h + kbg * 32);
                h8 al = *(const h8*)(arow_l + kbg * 32);
                a0 = MFMA16(ah, wh[kb4], a0);
                a1 = MFMA16(ah, wl[kb4], a1);
                a2 = MFMA16(al, wh[kb4], a2);
            }
            float* pre = kh ? &preB[0][0] : &preA[0][0];
            #pragma unroll
            for (int q = 0; q < 4; ++q)
                pre[(kg * 4 + q) * 64 + n_local] = a0[q] + (a1[q] + a2[q]) * (1.0f / 2048.0f);
            __syncthreads();

            if (tid < 256) {
                f32x4 gA = *(const f32x4*)&preA[cr][cjl * 4];
                f32x4 gB = *(const f32x4*)&preB[cr][cjl * 4];
                float pf = gA[0] + gB[0] + bb[0] + w1f_, pi = gA[1] + gB[1] + bb[1] + w1i_;
                float po = gA[2] + gB[2] + bb[2] + w1o_, pc = gA[3] + gB[3] + bb[3] + w1c_;
                float fg = fast_sigmoid(pf);
                float ig = fast_sigmoid(pi);
                float og = fast_sigmoid(po);
                float ct = tanhf(pc);
                creg = fmaf(fg, creg, ig * ct);
                float h = og * tanhf(creg);
                ASTORE(&y[(size_t)t * BV + (size_t)cb * V + 256 + cjg], h);
                if (t == T - 1) { H1t[cb * NH + cjg] = h; C1t[cb * NH + cjg] = creg; }
            }
        }
    }
}

// Y = H2_all @ Wout + bout, in place (block stages its 64 rows before writing).
__global__ __launch_bounds__(256) void k_ygemm2(
    float* __restrict__ y, const _Float16* __restrict__ pkY,
    const float* __restrict__ bout)
{
    __shared__ _Float16 Ah[64][264];
    __shared__ _Float16 Al[64][264];
    const size_t m0 = (size_t)blockIdx.x * 64;
    const int tid = threadIdx.x;
    for (int idx = tid; idx < 64 * 256; idx += 256) {
        int r = idx >> 8, k = idx & 255;
        float v = y[(m0 + r) * 1024 + k];
        _Float16 hi = (_Float16)v;
        Ah[r][k] = hi;
        Al[r][k] = (_Float16)((v - (float)hi) * 2048.0f);
    }
    __syncthreads();
    const int wave = tid >> 6, lane = tid & 63;
    const int col = lane & 15, kg = lane >> 4;
    const int ar = wave * 16 + col;
    const size_t orow = m0 + wave * 16 + kg * 4;
    for (int npass = 0; npass < 8; ++npass) {
        f32x4 aA[8], aB[8];
        #pragma unroll
        for (int nt = 0; nt < 8; ++nt) { aA[nt] = (f32x4){0.f,0.f,0.f,0.f}; aB[nt] = aA[nt]; }
        for (int kb = 0; kb < 8; ++kb) {
            h8 ah = *(const h8*)&Ah[ar][kb * 32 + kg * 8];
            h8 al = *(const h8*)&Al[ar][kb * 32 + kg * 8];
            #pragma unroll
            for (int nt = 0; nt < 8; ++nt) {
                const int ngrp = npass * 8 + nt;
                const _Float16* pb = pkY + ((size_t)(ngrp * 8 + kb) * 64 + lane) * 8;
                h8 bh = *(const h8*)pb;
                h8 bl = *(const h8*)(pb + 262144);
                aA[nt] = MFMA16(ah, bh, aA[nt]);
                aB[nt] = MFMA16(ah, bl, aB[nt]);
                aB[nt] = MFMA16(al, bh, aB[nt]);
            }
        }
        #pragma unroll
        for (int nt = 0; nt < 8; ++nt) {
            int n = npass * 128 + nt * 16 + col;
            float bbo = bout[n];
            #pragma unroll
            for (int q = 0; q < 4; ++q)
                y[(orow + q) * 1024 + n] = aA[nt][q] + aB[nt][q] * (1.0f / 2048.0f) + bbo;
        }
    }
}

// ---------------- launch ----------------
extern "C" void kernel_launch(void* const* d_in, const int* in_sizes, int n_in,
                              void* d_out, int out_size, void* d_ws, size_t ws_size,
                              hipStream_t stream) {
    const int*   X    = (const int*)  d_in[0];
    const float* H1in = (const float*)d_in[1];
    const float* C1in = (const float*)d_in[2];
    const float* H2in = (const float*)d_in[3];
    const float* C2in = (const float*)d_in[4];
    const float* W1f = (const float*)d_in[5];  const float* b1f = (const float*)d_in[6];
    const float* W1i = (const float*)d_in[7];  const float* b1i = (const float*)d_in[8];
    const float* W1o = (const float*)d_in[9];  const float* b1o = (const float*)d_in[10];
    const float* W1c = (const float*)d_in[11]; const float* b1c = (const float*)d_in[12];
    const float* W2f = (const float*)d_in[13]; const float* b2f = (const float*)d_in[14];
    const float* W2i = (const float*)d_in[15]; const float* b2i = (const float*)d_in[16];
    const float* W2o = (const float*)d_in[17]; const float* b2o = (const float*)d_in[18];
    const float* W2c = (const float*)d_in[19]; const float* b2c = (const float*)d_in[20];
    const float* Wout = (const float*)d_in[21]; const float* bout = (const float*)d_in[22];

    float* y   = (float*)d_out;
    float* H1t = y + YSZ;
    float* C1t = y + YSZ + 1 * 32768;
    float* H2t = y + YSZ + 2 * 32768;
    float* C2t = y + YSZ + 3 * 32768;

    char* ws = (char*)d_ws;
    _Float16* pk2 = (_Float16*)ws;
    _Float16* pk1 = pk2 + 1048576;
    _Float16* pkY = pk1 + 524288;
    float* bp2 = (float*)(ws + 4194304);
    float* bp1 = bp2 + 1024;

    k_prep<<<8200, 256, 0, stream>>>(W1f, W1i, W1o, W1c, W2f, W2i, W2o, W2c, Wout,
                                     b1f, b1i, b1o, b1c, b2f, b2i, b2o, b2c,
                                     pk2, pk1, pkY, bp2, bp1);
    k_sent<<<2048, 256, 0, stream>>>(y);

    k_persist<<<256, 512, 0, stream>>>(X, H1in, C1in, H2in, C2in, y,
                                       H1t, C1t, H2t, C2t,
                                       pk2, pk1, bp2, bp1,
                                       W1f, W1i, W1o, W1c);

    k_ygemm2<<<1024, 256, 0, stream>>>(y, pkY, bout);
}

// Round 11
// 2120.817 us; speedup vs baseline: 2.5660x; 1.0478x over previous
//
#include <hip/hip_runtime.h>
#include <math.h>

static constexpr int V  = 1024;
static constexpr int NH = 256;
static constexpr int B  = 128;
static constexpr int T  = 512;
static constexpr size_t BV  = (size_t)B * V;
static constexpr size_t YSZ = (size_t)T * B * V;   // 67,108,864
static constexpr unsigned SENT = 0xFFC0DEADu;      // NaN payload; h in (-1,1) never equals it

typedef _Float16 h8 __attribute__((ext_vector_type(8)));
typedef _Float16 h4 __attribute__((ext_vector_type(4)));
typedef float f32x4 __attribute__((ext_vector_type(4)));

#define MFMA16(a, b, c) __builtin_amdgcn_mfma_f32_16x16x32_f16((a), (b), (c), 0, 0, 0)
#define MALL_LD(dst, src) asm volatile("global_load_dwordx4 %0, %1, off sc0 sc1" : "=v"(dst) : "v"(src))

__device__ __forceinline__ void mall_store(float* p, f32x4 v) {
    asm volatile("global_store_dwordx4 %0, %1, off sc0 sc1" :: "v"(p), "v"(v) : "memory");
}

__device__ __forceinline__ float fast_sigmoid(float x) {
    float a = fminf(-1.442695041f * x, 126.0f);
    return __builtin_amdgcn_rcpf(1.0f + __builtin_amdgcn_exp2f(a));
}

__device__ __forceinline__ int has_sent(f32x4 v) {
    return (__float_as_uint(v[0]) == SENT) | (__float_as_uint(v[1]) == SENT) |
           (__float_as_uint(v[2]) == SENT) | (__float_as_uint(v[3]) == SENT);
}

__device__ __forceinline__ void cvtv(f32x4 u, h4* hi4, h4* lo4) {
    h4 hi, lo;
    #pragma unroll
    for (int e = 0; e < 4; ++e) {
        _Float16 h = (_Float16)u[e];
        hi[e] = h; lo[e] = (_Float16)((u[e] - (float)h) * 2048.0f);
    }
    *hi4 = hi; *lo4 = lo;
}

// Split-f16: x = hi + lo*2^-11, lo pre-scaled by 2048. Dot = hi*hi + (hi*lo + lo*hi)*2^-11.
// d_out: y[T*B][V], tails H1,C1,H2,C2. Stash: h2(t)->y[t][0:256], h1(t)->y[t][256:512].
// Sync = data-as-flag (SENT) with 16B MALL loads/stores (sc0 sc1) both sides.
// k_persist: 128 MERGED blocks x 512 thr; block (mp,np) owns 16 rows x 16 hidden
// of BOTH cells; staged h1(t) tile feeds cell2(t) AND cell1(t+1).

__global__ __launch_bounds__(256) void k_prep(
    const float* __restrict__ W1f, const float* __restrict__ W1i,
    const float* __restrict__ W1o, const float* __restrict__ W1c,
    const float* __restrict__ W2f, const float* __restrict__ W2i,
    const float* __restrict__ W2o, const float* __restrict__ W2c,
    const float* __restrict__ Wout,
    const float* __restrict__ b1f, const float* __restrict__ b1i,
    const float* __restrict__ b1o, const float* __restrict__ b1c,
    const float* __restrict__ b2f, const float* __restrict__ b2i,
    const float* __restrict__ b2o, const float* __restrict__ b2c,
    _Float16* __restrict__ pk2, _Float16* __restrict__ pk1,
    _Float16* __restrict__ pkY, float* __restrict__ bp2, float* __restrict__ bp1)
{
    int idx = blockIdx.x * 256 + threadIdx.x;
    if (idx < 2097152) {
        int KB, e, rowoff = 0;
        bool vocabN = false;
        _Float16* dst;
        if (idx < 1048576)      { e = idx;            KB = 16; dst = pk2; }
        else if (idx < 1572864) { e = idx - 1048576;  KB = 8;  dst = pk1; rowoff = V; }
        else                    { e = idx - 1572864;  KB = 8;  dst = pkY; vocabN = true; }
        int S = 64 * KB * 512;
        int split = e / S, r = e % S;
        int grp = r / (KB * 512);
        int r2  = r % (KB * 512);
        int kb = r2 >> 9, lane = (r2 >> 3) & 63, i = r2 & 7;
        int n = grp * 16 + (lane & 15);
        int k = kb * 32 + (lane >> 4) * 8 + i;
        float val;
        if (vocabN) {
            val = Wout[(size_t)k * 1024 + n];
        } else {
            int j = n >> 2, g = n & 3;
            const float* W = (KB == 16)
                ? (g == 0 ? W2f : g == 1 ? W2i : g == 2 ? W2o : W2c)
                : (g == 0 ? W1f : g == 1 ? W1i : g == 2 ? W1o : W1c);
            val = W[(size_t)(rowoff + k) * NH + j];
        }
        _Float16 hi = (_Float16)val;
        dst[e] = split ? (_Float16)((val - (float)hi) * 2048.0f) : hi;
    } else {
        int bi = idx - 2097152;
        if (bi < 1024) {
            int j = bi >> 2, g = bi & 3;
            bp2[bi] = (g == 0 ? b2f : g == 1 ? b2i : g == 2 ? b2o : b2c)[j];
        } else if (bi < 2048) {
            int b2_ = bi - 1024;
            int j = b2_ >> 2, g = b2_ & 3;
            bp1[b2_] = (g == 0 ? b1f : g == 1 ? b1i : g == 2 ? b1o : b1c)[j];
        }
    }
}

__global__ __launch_bounds__(256) void k_sent(float* __restrict__ y) {
    const float s = __uint_as_float(SENT);
    const f32x4 sv = {s, s, s, s};
    int gid = blockIdx.x * 256 + threadIdx.x;       // 524288 threads
    for (int n = gid; n < 8388608; n += 524288) {
        int row = n >> 7, c4 = n & 127;
        *(f32x4*)&y[(size_t)row * V + c4 * 4] = sv;
    }
}

// 128 merged blocks x 512 thr. Block (mp=bid>>4, np=bid&15): rows mp*16..+16,
// hidden cols np*16..+16 (gate cols np*64..+64) of BOTH cells, all t.
// Waves: wq=w&3 (16-gate-col group), kh=w>>2 (K-half).
__global__ __launch_bounds__(512, 1) void k_persist(
    const int* __restrict__ X,
    const float* __restrict__ H1in, const float* __restrict__ C1in,
    const float* __restrict__ H2in, const float* __restrict__ C2in,
    float* __restrict__ y,
    float* __restrict__ H1t, float* __restrict__ C1t,
    float* __restrict__ H2t, float* __restrict__ C2t,
    const _Float16* __restrict__ pk2, const _Float16* __restrict__ pk1,
    const float* __restrict__ bp2, const float* __restrict__ bp1,
    const float* __restrict__ W1f, const float* __restrict__ W1i,
    const float* __restrict__ W1o, const float* __restrict__ W1c)
{
    const int bid = blockIdx.x, tid = threadIdx.x;
    const int mp = bid >> 4, np = bid & 15, r0 = mp * 16;

    __shared__ _Float16 Ah[16][520];
    __shared__ _Float16 Al[16][520];
    __shared__ float p1A[16][64], p1B[16][64], p2A[16][64], p2B[16][64];

    const int wave = tid >> 6, lane = tid & 63;
    const int wq = wave & 3, kh = wave >> 2;
    const int col = lane & 15, kg = lane >> 4;
    const int n_local = wq * 16 + col;

    // ---- weights: cell1 K-half 8 h8 (32 VGPR), cell2 K-half 16 h8 (64 VGPR) ----
    h8 wh1[4], wl1[4], wh2[8], wl2[8];
    {
        const _Float16* pB1 = pk1 + ((size_t)((np * 4 + wq) * 8 + kh * 4) * 64 + lane) * 8;
        #pragma unroll
        for (int kb = 0; kb < 4; ++kb) {
            wh1[kb] = *(const h8*)(pB1 + (size_t)kb * 512);
            wl1[kb] = *(const h8*)(pB1 + 262144 + (size_t)kb * 512);
        }
        const _Float16* pB2 = pk2 + ((size_t)((np * 4 + wq) * 16 + kh * 8) * 64 + lane) * 8;
        #pragma unroll
        for (int kb = 0; kb < 8; ++kb) {
            wh2[kb] = *(const h8*)(pB2 + (size_t)kb * 512);
            wl2[kb] = *(const h8*)(pB2 + 524288 + (size_t)kb * 512);
        }
        #pragma unroll
        for (int kb = 0; kb < 4; ++kb) asm volatile("" : "+v"(wh1[kb]), "+v"(wl1[kb]));
        #pragma unroll
        for (int kb = 0; kb < 8; ++kb) asm volatile("" : "+v"(wh2[kb]), "+v"(wl2[kb]));
    }

    // combine roles: tid<256 -> cell1 (c1), tid>=256 -> cell2 (c2)
    const bool isCmb1 = tid < 256;
    const int ct = isCmb1 ? tid : (tid - 256);
    const int cr = ct >> 4, cjl = ct & 15;
    const int cb = r0 + cr, cjg = np * 16 + cjl;
    float creg = isCmb1 ? C1in[cb * NH + cjg] : C2in[cb * NH + cjg];
    const f32x4 bb = *(const f32x4*)&((isCmb1 ? bp1 : bp2)[np * 64 + cjl * 4]);

    // staging: sk4 = tid&63 (c4 within 256 cols), rows srb, srb+8
    const int sk4 = tid & 63;
    const int srb = tid >> 6;   // 0..7

    // ================= pre-loop: cell1(0) from H1in =================
    {
        f32x4 ua = *(const f32x4*)(H1in + (size_t)(r0 + srb) * NH + sk4 * 4);
        f32x4 ub = *(const f32x4*)(H1in + (size_t)(r0 + srb + 8) * NH + sk4 * 4);
        cvtv(ua, (h4*)&Ah[srb][sk4 * 4], (h4*)&Al[srb][sk4 * 4]);
        cvtv(ub, (h4*)&Ah[srb + 8][sk4 * 4], (h4*)&Al[srb + 8][sk4 * 4]);
        __syncthreads();
        f32x4 a0 = {0.f, 0.f, 0.f, 0.f}, a1 = a0, a2 = a0;
        #pragma unroll
        for (int kb = 0; kb < 4; ++kb) {
            const int kbg = kh * 4 + kb;
            h8 ah = *(const h8*)&Ah[col][kbg * 32 + kg * 8];
            h8 al = *(const h8*)&Al[col][kbg * 32 + kg * 8];
            a0 = MFMA16(ah, wh1[kb], a0);
            a1 = MFMA16(ah, wl1[kb], a1);
            a2 = MFMA16(al, wh1[kb], a2);
        }
        float* pre = kh ? &p1B[0][0] : &p1A[0][0];
        #pragma unroll
        for (int q = 0; q < 4; ++q)
            pre[(kg * 4 + q) * 64 + n_local] = a0[q] + (a1[q] + a2[q]) * (1.0f / 2048.0f);
        __syncthreads();
        if (isCmb1) {
            int tok = X[cb * T + 0];
            float pf = p1A[cr][cjl * 4 + 0] + p1B[cr][cjl * 4 + 0] + bb[0] + W1f[(size_t)tok * NH + cjg];
            float pi = p1A[cr][cjl * 4 + 1] + p1B[cr][cjl * 4 + 1] + bb[1] + W1i[(size_t)tok * NH + cjg];
            float po = p1A[cr][cjl * 4 + 2] + p1B[cr][cjl * 4 + 2] + bb[2] + W1o[(size_t)tok * NH + cjg];
            float pc = p1A[cr][cjl * 4 + 3] + p1B[cr][cjl * 4 + 3] + bb[3] + W1c[(size_t)tok * NH + cjg];
            float fg = fast_sigmoid(pf), ig = fast_sigmoid(pi), og = fast_sigmoid(po);
            creg = fmaf(fg, creg, ig * tanhf(pc));
            float h = og * tanhf(creg);
            float h1n = __shfl(h, (lane & 60) | 1);
            float h2n = __shfl(h, (lane & 60) | 2);
            float h3n = __shfl(h, (lane & 60) | 3);
            if ((lane & 3) == 0) {
                f32x4 hv = {h, h1n, h2n, h3n};
                mall_store(y + (size_t)cb * V + 256 + cjg, hv);
            }
        }
    }

    // ================= main loop =================
    for (int t = 0; t < T; ++t) {
        // token gather for cell1(t+1), issued early
        float w1f_ = 0.f, w1i_ = 0.f, w1o_ = 0.f, w1c_ = 0.f;
        if (isCmb1 && t <= 510) {
            int tok = X[cb * T + t + 1];
            w1f_ = W1f[(size_t)tok * NH + cjg];
            w1i_ = W1i[(size_t)tok * NH + cjg];
            w1o_ = W1o[(size_t)tok * NH + cjg];
            w1c_ = W1c[(size_t)tok * NH + cjg];
        }

        // ---- poll+stage: h1(t) -> cols 0..255, h2(t-1) -> cols 256..511 ----
        f32x4 u1a, u1b, u2a, u2b;
        const float* p1a = y + (size_t)t * BV + (size_t)(r0 + srb) * V + 256 + sk4 * 4;
        const float* p1b = y + (size_t)t * BV + (size_t)(r0 + srb + 8) * V + 256 + sk4 * 4;
        if (t) {
            const float* p2a = y + (size_t)(t - 1) * BV + (size_t)(r0 + srb) * V + sk4 * 4;
            const float* p2b = y + (size_t)(t - 1) * BV + (size_t)(r0 + srb + 8) * V + sk4 * 4;
            MALL_LD(u2a, p2a); MALL_LD(u2b, p2b); MALL_LD(u1a, p1a); MALL_LD(u1b, p1b);
            asm volatile("s_waitcnt vmcnt(0)" : "+v"(u2a), "+v"(u2b), "+v"(u1a), "+v"(u1b));
            while (__any(has_sent(u1a) | has_sent(u1b) | has_sent(u2a) | has_sent(u2b))) {
                __builtin_amdgcn_s_sleep(1);
                MALL_LD(u2a, p2a); MALL_LD(u2b, p2b); MALL_LD(u1a, p1a); MALL_LD(u1b, p1b);
                asm volatile("s_waitcnt vmcnt(0)" : "+v"(u2a), "+v"(u2b), "+v"(u1a), "+v"(u1b));
            }
        } else {
            MALL_LD(u1a, p1a); MALL_LD(u1b, p1b);
            asm volatile("s_waitcnt vmcnt(0)" : "+v"(u1a), "+v"(u1b));
            while (__any(has_sent(u1a) | has_sent(u1b))) {
                __builtin_amdgcn_s_sleep(1);
                MALL_LD(u1a, p1a); MALL_LD(u1b, p1b);
                asm volatile("s_waitcnt vmcnt(0)" : "+v"(u1a), "+v"(u1b));
            }
            u2a = *(const f32x4*)(H2in + (size_t)(r0 + srb) * NH + sk4 * 4);
            u2b = *(const f32x4*)(H2in + (size_t)(r0 + srb + 8) * NH + sk4 * 4);
        }
        cvtv(u1a, (h4*)&Ah[srb][sk4 * 4], (h4*)&Al[srb][sk4 * 4]);
        cvtv(u1b, (h4*)&Ah[srb + 8][sk4 * 4], (h4*)&Al[srb + 8][sk4 * 4]);
        cvtv(u2a, (h4*)&Ah[srb][256 + sk4 * 4], (h4*)&Al[srb][256 + sk4 * 4]);
        cvtv(u2b, (h4*)&Ah[srb + 8][256 + sk4 * 4], (h4*)&Al[srb + 8][256 + sk4 * 4]);
        __syncthreads();   // sync1

        // ---- phase 1: cell1(t+1) MFMA (K=256, cols 0..255) ----
        {
            f32x4 a0 = {0.f, 0.f, 0.f, 0.f}, a1 = a0, a2 = a0;
            #pragma unroll
            for (int kb = 0; kb < 4; ++kb) {
                const int kbg = kh * 4 + kb;
                h8 ah = *(const h8*)&Ah[col][kbg * 32 + kg * 8];
                h8 al = *(const h8*)&Al[col][kbg * 32 + kg * 8];
                a0 = MFMA16(ah, wh1[kb], a0);
                a1 = MFMA16(ah, wl1[kb], a1);
                a2 = MFMA16(al, wh1[kb], a2);
            }
            float* pre = kh ? &p1B[0][0] : &p1A[0][0];
            #pragma unroll
            for (int q = 0; q < 4; ++q)
                pre[(kg * 4 + q) * 64 + n_local] = a0[q] + (a1[q] + a2[q]) * (1.0f / 2048.0f);
        }
        __syncthreads();   // sync2

        // ---- cell1 combine + h1(t+1) store (critical chain) ----
        if (isCmb1 && t <= 510) {
            float pf = p1A[cr][cjl * 4 + 0] + p1B[cr][cjl * 4 + 0] + bb[0] + w1f_;
            float pi = p1A[cr][cjl * 4 + 1] + p1B[cr][cjl * 4 + 1] + bb[1] + w1i_;
            float po = p1A[cr][cjl * 4 + 2] + p1B[cr][cjl * 4 + 2] + bb[2] + w1o_;
            float pc = p1A[cr][cjl * 4 + 3] + p1B[cr][cjl * 4 + 3] + bb[3] + w1c_;
            float fg = fast_sigmoid(pf), ig = fast_sigmoid(pi), og = fast_sigmoid(po);
            creg = fmaf(fg, creg, ig * tanhf(pc));
            float h = og * tanhf(creg);
            float h1n = __shfl(h, (lane & 60) | 1);
            float h2n = __shfl(h, (lane & 60) | 2);
            float h3n = __shfl(h, (lane & 60) | 3);
            if ((lane & 3) == 0) {
                f32x4 hv = {h, h1n, h2n, h3n};
                mall_store(y + (size_t)(t + 1) * BV + (size_t)cb * V + 256 + cjg, hv);
            }
            if (t == 510) { H1t[cb * NH + cjg] = h; C1t[cb * NH + cjg] = creg; }
        }

        // ---- phase 2: cell2(t) MFMA (K=512, full tile) ----
        {
            f32x4 a0 = {0.f, 0.f, 0.f, 0.f}, a1 = a0, a2 = a0;
            #pragma unroll
            for (int kb = 0; kb < 8; ++kb) {
                const int kbg = kh * 8 + kb;
                h8 ah = *(const h8*)&Ah[col][kbg * 32 + kg * 8];
                h8 al = *(const h8*)&Al[col][kbg * 32 + kg * 8];
                a0 = MFMA16(ah, wh2[kb], a0);
                a1 = MFMA16(ah, wl2[kb], a1);
                a2 = MFMA16(al, wh2[kb], a2);
            }
            float* pre = kh ? &p2B[0][0] : &p2A[0][0];
            #pragma unroll
            for (int q = 0; q < 4; ++q)
                pre[(kg * 4 + q) * 64 + n_local] = a0[q] + (a1[q] + a2[q]) * (1.0f / 2048.0f);
        }
        __syncthreads();   // sync3

        // ---- cell2 combine + h2(t) store ----
        if (!isCmb1) {
            float pf = p2A[cr][cjl * 4 + 0] + p2B[cr][cjl * 4 + 0] + bb[0];
            float pi = p2A[cr][cjl * 4 + 1] + p2B[cr][cjl * 4 + 1] + bb[1];
            float po = p2A[cr][cjl * 4 + 2] + p2B[cr][cjl * 4 + 2] + bb[2];
            float pc = p2A[cr][cjl * 4 + 3] + p2B[cr][cjl * 4 + 3] + bb[3];
            float fg = fast_sigmoid(pf), ig = fast_sigmoid(pi), og = fast_sigmoid(po);
            creg = fmaf(fg, creg, ig * tanhf(pc));
            float h = og * tanhf(creg);
            float h1n = __shfl(h, (lane & 60) | 1);
            float h2n = __shfl(h, (lane & 60) | 2);
            float h3n = __shfl(h, (lane & 60) | 3);
            if ((lane & 3) == 0) {
                f32x4 hv = {h, h1n, h2n, h3n};
                mall_store(y + (size_t)t * BV + (size_t)cb * V + cjg, hv);
            }
            if (t == 511) { H2t[cb * NH + cjg] = h; C2t[cb * NH + cjg] = creg; }
        }
    }
}

// Y = H2_all @ Wout + bout, in place (block stages its 64 rows before writing).
__global__ __launch_bounds__(256) void k_ygemm2(
    float* __restrict__ y, const _Float16* __restrict__ pkY,
    const float* __restrict__ bout)
{
    __shared__ _Float16 Ah[64][264];
    __shared__ _Float16 Al[64][264];
    const size_t m0 = (size_t)blockIdx.x * 64;
    const int tid = threadIdx.x;
    for (int idx = tid; idx < 64 * 256; idx += 256) {
        int r = idx >> 8, k = idx & 255;
        float v = y[(m0 + r) * 1024 + k];
        _Float16 hi = (_Float16)v;
        Ah[r][k] = hi;
        Al[r][k] = (_Float16)((v - (float)hi) * 2048.0f);
    }
    __syncthreads();
    const int wave = tid >> 6, lane = tid & 63;
    const int col = lane & 15, kg = lane >> 4;
    const int ar = wave * 16 + col;
    const size_t orow = m0 + wave * 16 + kg * 4;
    for (int npass = 0; npass < 8; ++npass) {
        f32x4 aA[8], aB[8];
        #pragma unroll
        for (int nt = 0; nt < 8; ++nt) { aA[nt] = (f32x4){0.f,0.f,0.f,0.f}; aB[nt] = aA[nt]; }
        for (int kb = 0; kb < 8; ++kb) {
            h8 ah = *(const h8*)&Ah[ar][kb * 32 + kg * 8];
            h8 al = *(const h8*)&Al[ar][kb * 32 + kg * 8];
            #pragma unroll
            for (int nt = 0; nt < 8; ++nt) {
                const int ngrp = npass * 8 + nt;
                const _Float16* pb = pkY + ((size_t)(ngrp * 8 + kb) * 64 + lane) * 8;
                h8 bh = *(const h8*)pb;
                h8 bl = *(const h8*)(pb + 262144);
                aA[nt] = MFMA16(ah, bh, aA[nt]);
                aB[nt] = MFMA16(ah, bl, aB[nt]);
                aB[nt] = MFMA16(al, bh, aB[nt]);
            }
        }
        #pragma unroll
        for (int nt = 0; nt < 8; ++nt) {
            int n = npass * 128 + nt * 16 + col;
            float bbo = bout[n];
            #pragma unroll
            for (int q = 0; q < 4; ++q)
                y[(orow + q) * 1024 + n] = aA[nt][q] + aB[nt][q] * (1.0f / 2048.0f) + bbo;
        }
    }
}

// ---------------- launch ----------------
extern "C" void kernel_launch(void* const* d_in, const int* in_sizes, int n_in,
                              void* d_out, int out_size, void* d_ws, size_t ws_size,
                              hipStream_t stream) {
    const int*   X    = (const int*)  d_in[0];
    const float* H1in = (const float*)d_in[1];
    const float* C1in = (const float*)d_in[2];
    const float* H2in = (const float*)d_in[3];
    const float* C2in = (const float*)d_in[4];
    const float* W1f = (const float*)d_in[5];  const float* b1f = (const float*)d_in[6];
    const float* W1i = (const float*)d_in[7];  const float* b1i = (const float*)d_in[8];
    const float* W1o = (const float*)d_in[9];  const float* b1o = (const float*)d_in[10];
    const float* W1c = (const float*)d_in[11]; const float* b1c = (const float*)d_in[12];
    const float* W2f = (const float*)d_in[13]; const float* b2f = (const float*)d_in[14];
    const float* W2i = (const float*)d_in[15]; const float* b2i = (const float*)d_in[16];
    const float* W2o = (const float*)d_in[17]; const float* b2o = (const float*)d_in[18];
    const float* W2c = (const float*)d_in[19]; const float* b2c = (const float*)d_in[20];
    const float* Wout = (const float*)d_in[21]; const float* bout = (const float*)d_in[22];

    float* y   = (float*)d_out;
    float* H1t = y + YSZ;
    float* C1t = y + YSZ + 1 * 32768;
    float* H2t = y + YSZ + 2 * 32768;
    float* C2t = y + YSZ + 3 * 32768;

    char* ws = (char*)d_ws;
    _Float16* pk2 = (_Float16*)ws;
    _Float16* pk1 = pk2 + 1048576;
    _Float16* pkY = pk1 + 524288;
    float* bp2 = (float*)(ws + 4194304);
    float* bp1 = bp2 + 1024;

    k_prep<<<8200, 256, 0, stream>>>(W1f, W1i, W1o, W1c, W2f, W2i, W2o, W2c, Wout,
                                     b1f, b1i, b1o, b1c, b2f, b2i, b2o, b2c,
                                     pk2, pk1, pkY, bp2, bp1);
    k_sent<<<2048, 256, 0, stream>>>(y);

    k_persist<<<128, 512, 0, stream>>>(X, H1in, C1in, H2in, C2in, y,
                                       H1t, C1t, H2t, C2t,
                                       pk2, pk1, bp2, bp1,
                                       W1f, W1i, W1o, W1c);

    k_ygemm2<<<1024, 256, 0, stream>>>(y, pkY, bout);
}